// Round 5
// baseline (51.192 us; speedup 1.0000x reference)
//
#include <hip/hip_runtime.h>

// Involution b=8, c=64, h=w=128, K=3, G=8, r=2.
// kern = Wc @ x_center + bb, Wc = w_span@w_reduce (72x64), bb = w_span@b_reduce + b_span.
// R12 = R11 (2 px/thread, octant split, 2048 blocks, XCD swizzle) with DEEP
//   LOAD BATCHING — attack latency-volley serialization:
//   - Phase A: 16-ch clusters; loads for clusters k and k+1 issued before
//     cluster k's FMA block (32 float2 in flight; 288-cy FMA hides next volley).
//   - Phase B: ALL 72 tap loads issued before any FMA (one exposed round-trip
//     instead of 8 serialized per-channel volleys).
//   All arrays static-indexed + fully unrolled (R8 lesson). VGPR is INTENDED
//   to rise to ~110-128; watch WRITE_SIZE for spill (must stay 32768 KB).
// Ledger: R9 (fewer VALU) flat->worse; R10 (PhB via LDS) flat; R11 (2px) flat;
//   VGPR 36-44 in all => compiler serialized round-trips; this forces MLP.

#define HW 16384   // 128*128
#define WPX 128

// ws layout: [0,72) bb ;  [72 + o*576 + c*9 + j) Wg[o][c][j]   (o=group 0..7)
__global__ void invol_setup(const float* __restrict__ w_reduce,
                            const float* __restrict__ b_reduce,
                            const float* __restrict__ w_span,
                            const float* __restrict__ b_span,
                            float* __restrict__ ws)
{
    const int tid = blockIdx.x * 256 + threadIdx.x;   // 0..4607
    if (tid >= 72 * 64) return;
    const int row = tid >> 6;     // 0..71  (= g*9 + j)
    const int c   = tid & 63;
    float s = 0.f;
#pragma unroll
    for (int i = 0; i < 32; ++i)
        s = fmaf(w_span[row * 32 + i], w_reduce[i * 64 + c], s);
    ws[72 + (row / 9) * 576 + c * 9 + (row % 9)] = s;
    if (c == 0) {
        float t = b_span[row];
#pragma unroll
        for (int i = 0; i < 32; ++i)
            t = fmaf(w_span[row * 32 + i], b_reduce[i], t);
        ws[row] = t;
    }
}

// load 16 float2 (channels C0..C0+15) into XV
#define PHA_LD(XV, C0)                                                        \
    _Pragma("unroll")                                                         \
    for (int i = 0; i < 16; ++i)                                              \
        XV[i] = *reinterpret_cast<const float2*>(xb + (size_t)((C0) + i) * HW);

// 16 channels x 9 outputs x 2 pixels of FMA
#define PHA_FMA(XV, C0)                                                       \
    _Pragma("unroll")                                                         \
    for (int i = 0; i < 16; ++i) {                                            \
        _Pragma("unroll")                                                     \
        for (int j = 0; j < 9; ++j) {                                         \
            const float wv = Wg[((C0) + i) * 9 + j];                          \
            kg[j].x = fmaf(wv, XV[i].x, kg[j].x);                             \
            kg[j].y = fmaf(wv, XV[i].y, kg[j].y);                             \
        }                                                                     \
    }

__global__ __launch_bounds__(256, 4) void invol_main(
    const float* __restrict__ x,
    const float* __restrict__ ws,
    float* __restrict__ out)
{
    // XCD-aware swizzle: nwg = 2048, 8 XCDs, 256 logical ids per XCD.
    const int bid     = blockIdx.x;
    const int logical = (bid & 7) * 256 + (bid >> 3);
    const int o  = logical & 7;             // octant / group — SCALAR (SGPR)
    const int pb = logical >> 3;            // pair-block (256 pixel-pairs)

    const int P2  = pb * 256 + threadIdx.x; // pixel-pair id, 0..65535
    const int b   = P2 >> 13;               // 8192 pairs per image
    const int hw0 = (P2 & 8191) << 1;       // even pixel index
    const int h   = hw0 >> 7;
    const int w0  = hw0 & 127;              // even, 0..126

    const size_t imgoff = (size_t)b * 64 * HW;
    const float* xb  = x + imgoff + hw0;
    const float* Wg  = ws + 72 + o * 576;   // [c][9], scalar base
    const float* bbg = ws + o * 9;          // group bias, 9 floats

    // ---- phase A: 4 clusters of 16, double-buffered (2 volleys in flight) ----
    float2 kg[9];
#pragma unroll
    for (int j = 0; j < 9; ++j) { const float t = bbg[j]; kg[j] = make_float2(t, t); }

    {
        float2 xv0[16], xv1[16];
        PHA_LD(xv0, 0)
        PHA_LD(xv1, 16)
        PHA_FMA(xv0, 0)
        PHA_LD(xv0, 32)
        PHA_FMA(xv1, 16)
        PHA_LD(xv1, 48)
        PHA_FMA(xv0, 32)
        PHA_FMA(xv1, 48)
    }

    // ---- phase B prep: row-clamped offsets, masks folded into taps ----
    int rof[3];
#pragma unroll
    for (int t = 0; t < 3; ++t) {
        const int hh = h + t - 1;
        const int hc = hh < 0 ? 0 : (hh > 127 ? 127 : hh);
        rof[t] = (hc - h) * WPX;
        const float m = ((unsigned)hh < 128u) ? 1.f : 0.f;
#pragma unroll
        for (int d = 0; d < 3; ++d) { kg[t * 3 + d].x *= m; kg[t * 3 + d].y *= m; }
    }
    // column edges: px0 (w=w0) loses left taps only at w0==0; px1 (w=w0+1)
    // loses right taps only at w0==126. Edge loads are clamped in-bounds;
    // the clamped (finite) value is multiplied by a zeroed tap.
    const int dwl = (w0 == 0)   ? 0 : -1;   // col of left scalar load rel. w0
    const int dwr = (w0 == 126) ? 1 : 2;    // col of right scalar load rel. w0
    if (w0 == 0)   { kg[0].x = 0.f; kg[3].x = 0.f; kg[6].x = 0.f; }
    if (w0 == 126) { kg[2].y = 0.f; kg[5].y = 0.f; kg[8].y = 0.f; }

    // ---- phase B: ALL 72 tap loads first (one volley), then 144 FMA + stores ----
    float2 vC[24];           // [ci*3 + t]
    float  vL[24], vR[24];
#pragma unroll
    for (int ci = 0; ci < 8; ++ci) {
        const float* xc = xb + (size_t)(o * 8 + ci) * HW;
#pragma unroll
        for (int t = 0; t < 3; ++t) {
            vC[ci * 3 + t] = *reinterpret_cast<const float2*>(xc + rof[t]);
            vL[ci * 3 + t] = xc[rof[t] + dwl];
            vR[ci * 3 + t] = xc[rof[t] + dwr];
        }
    }
#pragma unroll
    for (int ci = 0; ci < 8; ++ci) {
        float acc0 = 0.f, acc1 = 0.f;
#pragma unroll
        for (int t = 0; t < 3; ++t) {
            acc0 = fmaf(kg[t * 3 + 0].x, vL[ci * 3 + t],   acc0);
            acc0 = fmaf(kg[t * 3 + 1].x, vC[ci * 3 + t].x, acc0);
            acc0 = fmaf(kg[t * 3 + 2].x, vC[ci * 3 + t].y, acc0);
            acc1 = fmaf(kg[t * 3 + 0].y, vC[ci * 3 + t].x, acc1);
            acc1 = fmaf(kg[t * 3 + 1].y, vC[ci * 3 + t].y, acc1);
            acc1 = fmaf(kg[t * 3 + 2].y, vR[ci * 3 + t],   acc1);
        }
        *reinterpret_cast<float2*>(out + imgoff + (size_t)(o * 8 + ci) * HW + hw0) =
            make_float2(acc0, acc1);
    }
}

// fallback (round-1 kernel) if ws is too small for the weight scratch
__global__ __launch_bounds__(256) void invol_fused_fallback(
    const float* __restrict__ x,
    const float* __restrict__ w_reduce,
    const float* __restrict__ b_reduce,
    const float* __restrict__ w_span,
    const float* __restrict__ b_span,
    float* __restrict__ out)
{
    const int pid = blockIdx.x * 256 + threadIdx.x;
    const int b  = pid >> 14;
    const int hw = pid & 16383;
    const int h  = hw >> 7;
    const int w  = hw & 127;
    const float* xb   = x   + (size_t)b * 64 * HW + hw;
    float*       outb = out + (size_t)b * 64 * HW + hw;
    float y[32];
#pragma unroll
    for (int o = 0; o < 32; ++o) y[o] = b_reduce[o];
#pragma unroll 4
    for (int c = 0; c < 64; ++c) {
        const float xc = xb[(size_t)c * HW];
#pragma unroll
        for (int o = 0; o < 32; ++o)
            y[o] = fmaf(w_reduce[o * 64 + c], xc, y[o]);
    }
    for (int g = 0; g < 8; ++g) {
        float kg[9];
#pragma unroll
        for (int k = 0; k < 9; ++k) {
            float s = b_span[g * 9 + k];
#pragma unroll
            for (int i = 0; i < 32; ++i)
                s = fmaf(w_span[(g * 9 + k) * 32 + i], y[i], s);
            kg[k] = s;
        }
#pragma unroll
        for (int ci = 0; ci < 8; ++ci) {
            const int c = g * 8 + ci;
            const float* xc = xb + (size_t)c * HW;
            float acc = 0.f;
#pragma unroll
            for (int k = 0; k < 9; ++k) {
                const int dh = k / 3 - 1, dw = k % 3 - 1;
                const int hh = h + dh, ww = w + dw;
                float v = ((unsigned)hh < 128u && (unsigned)ww < 128u)
                          ? xc[dh * WPX + dw] : 0.f;
                acc = fmaf(kg[k], v, acc);
            }
            outb[(size_t)c * HW] = acc;
        }
    }
}

extern "C" void kernel_launch(void* const* d_in, const int* in_sizes, int n_in,
                              void* d_out, int out_size, void* d_ws, size_t ws_size,
                              hipStream_t stream) {
    const float* x        = (const float*)d_in[0];
    const float* w_reduce = (const float*)d_in[1];
    const float* b_reduce = (const float*)d_in[2];
    const float* w_span   = (const float*)d_in[3];
    const float* b_span   = (const float*)d_in[4];
    float* out = (float*)d_out;

    const size_t ws_needed = (size_t)(72 + 8 * 64 * 9) * sizeof(float);  // 18720 B
    if (ws_size >= ws_needed) {
        float* ws = (float*)d_ws;
        invol_setup<<<18, 256, 0, stream>>>(w_reduce, b_reduce, w_span, b_span, ws);
        const int npairs = 8 * 128 * 128 / 2;          // 65536
        invol_main<<<npairs / 256 * 8, 256, 0, stream>>>(x, ws, out);  // 2048 blocks
    } else {
        const int npix = 8 * 128 * 128;
        invol_fused_fallback<<<npix / 256, 256, 0, stream>>>(
            x, w_reduce, b_reduce, w_span, b_span, out);
    }
}